// Round 1
// baseline (1950.805 us; speedup 1.0000x reference)
//
#include <hip/hip_runtime.h>
#include <cstddef>

// Problem constants (B=2, T=2048, D=1024, H=16, hd=64)
constexpr int B_ = 2, T_ = 2048, D_ = 1024, H_ = 16, HD_ = 64;

// ---------------------------------------------------------------------------
// Generic fp32 tiled GEMM: C[M,N] = A[M,K] * B[K,N], row-major.
// Requires M%64==0, N%64==0, K%16==0. 64x64 tile, 256 threads, 4x4 per thread.
// LDS layout [k][m]/[k][n] with stride 65 (odd mod 32 -> conflict-free scalar
// column reads; stores are scalar to avoid misaligned b128).
// ---------------------------------------------------------------------------
__global__ __launch_bounds__(256) void gemm_tiled(const float* __restrict__ A,
                                                  const float* __restrict__ Bm,
                                                  float* __restrict__ C,
                                                  int M, int N, int K) {
    __shared__ float As[16][65];  // [k][m]
    __shared__ float Bs[16][65];  // [k][n]
    const int tid = threadIdx.x;
    const int tx = tid & 15, ty = tid >> 4;
    const int bm = blockIdx.y * 64, bn = blockIdx.x * 64;
    float acc[4][4] = {};
    const int arow = tid >> 2, akq = (tid & 3) * 4;   // A: 64 rows x 16 k
    const int bkb = tid >> 4, bn4 = (tid & 15) * 4;   // B: 16 k x 64 n
    for (int k0 = 0; k0 < K; k0 += 16) {
        float4 av = *(const float4*)&A[(size_t)(bm + arow) * K + k0 + akq];
        float4 bv = *(const float4*)&Bm[(size_t)(k0 + bkb) * N + bn + bn4];
        As[akq + 0][arow] = av.x;
        As[akq + 1][arow] = av.y;
        As[akq + 2][arow] = av.z;
        As[akq + 3][arow] = av.w;
        Bs[bkb][bn4 + 0] = bv.x;
        Bs[bkb][bn4 + 1] = bv.y;
        Bs[bkb][bn4 + 2] = bv.z;
        Bs[bkb][bn4 + 3] = bv.w;
        __syncthreads();
#pragma unroll
        for (int kk = 0; kk < 16; kk++) {
            float a[4], b[4];
#pragma unroll
            for (int i = 0; i < 4; i++) a[i] = As[kk][ty * 4 + i];
#pragma unroll
            for (int j = 0; j < 4; j++) b[j] = Bs[kk][tx * 4 + j];
#pragma unroll
            for (int i = 0; i < 4; i++)
#pragma unroll
                for (int j = 0; j < 4; j++) acc[i][j] += a[i] * b[j];
        }
        __syncthreads();
    }
#pragma unroll
    for (int i = 0; i < 4; i++) {
        *(float4*)&C[(size_t)(bm + ty * 4 + i) * N + bn + tx * 4] =
            make_float4(acc[i][0], acc[i][1], acc[i][2], acc[i][3]);
    }
}

// ---------------------------------------------------------------------------
// scores[b,h,k,q] = (1/8) * sum_d K[b,h,k,d]*Q[b,h,q,d] + (q>k ? -1e9 : 0)
// K/Q live inside res [B*T, 3D]: K at col h*64, Q at col D + h*64.
// Blocks fully above the diagonal just write -1e9 (softmax will zero them).
// ---------------------------------------------------------------------------
__global__ __launch_bounds__(256) void scores_kernel(const float* __restrict__ res,
                                                     float* __restrict__ attn) {
    const int bh = blockIdx.z;
    const int b = bh >> 4, h = bh & 15;
    const int bk = blockIdx.y * 64, bq = blockIdx.x * 64;
    const int tid = threadIdx.x;
    const int tx = tid & 15, ty = tid >> 4;
    float* S = attn + (size_t)bh * T_ * T_;
    if (bq >= bk + 64) {  // entire block masked (q > k everywhere)
        const float4 mv = make_float4(-1e9f, -1e9f, -1e9f, -1e9f);
#pragma unroll
        for (int i = 0; i < 4; i++)
            *(float4*)&S[(size_t)(bk + ty * 4 + i) * T_ + bq + tx * 4] = mv;
        return;
    }
    __shared__ float Ks[64][65];  // [k][d]
    __shared__ float Qs[64][65];  // [q][d]
    const float* Kg = res + (size_t)b * T_ * (3 * D_) + h * HD_;
    const float* Qg = Kg + D_;
#pragma unroll
    for (int i = 0; i < 4; i++) {
        int f = tid + i * 256;            // 1024 float4-sized chunks? no: 1024 rows*16 float4
        int r = f >> 4, c4 = (f & 15) * 4;
        float4 kv = *(const float4*)&Kg[(size_t)(bk + r) * (3 * D_) + c4];
        float4 qv = *(const float4*)&Qg[(size_t)(bq + r) * (3 * D_) + c4];
        Ks[r][c4 + 0] = kv.x; Ks[r][c4 + 1] = kv.y;
        Ks[r][c4 + 2] = kv.z; Ks[r][c4 + 3] = kv.w;
        Qs[r][c4 + 0] = qv.x; Qs[r][c4 + 1] = qv.y;
        Qs[r][c4 + 2] = qv.z; Qs[r][c4 + 3] = qv.w;
    }
    __syncthreads();
    float acc[4][4] = {};
#pragma unroll 16
    for (int dd = 0; dd < 64; dd++) {
        float a[4], qb[4];
#pragma unroll
        for (int i = 0; i < 4; i++) a[i] = Ks[ty * 4 + i][dd];
#pragma unroll
        for (int j = 0; j < 4; j++) qb[j] = Qs[tx * 4 + j][dd];
#pragma unroll
        for (int i = 0; i < 4; i++)
#pragma unroll
            for (int j = 0; j < 4; j++) acc[i][j] += a[i] * qb[j];
    }
#pragma unroll
    for (int i = 0; i < 4; i++) {
        int k = bk + ty * 4 + i;
        float vals[4];
#pragma unroll
        for (int j = 0; j < 4; j++) {
            int q = bq + tx * 4 + j;
            vals[j] = acc[i][j] * 0.125f + (q > k ? -1e9f : 0.0f);
        }
        *(float4*)&S[(size_t)k * T_ + bq + tx * 4] =
            make_float4(vals[0], vals[1], vals[2], vals[3]);
    }
}

// ---------------------------------------------------------------------------
// In-place row softmax over the last axis (row length T=2048). 1 block/row.
// ---------------------------------------------------------------------------
__global__ __launch_bounds__(256) void softmax_kernel(float* __restrict__ attn) {
    const size_t row = blockIdx.x;
    float* p = attn + row * (size_t)T_;
    const int t = threadIdx.x;
    float v[8];
    float m = -3.0e38f;
#pragma unroll
    for (int i = 0; i < 8; i++) {
        v[i] = p[t + i * 256];
        m = fmaxf(m, v[i]);
    }
#pragma unroll
    for (int off = 32; off > 0; off >>= 1) m = fmaxf(m, __shfl_down(m, off, 64));
    __shared__ float redm[4], reds[4];
    const int wave = t >> 6, lane = t & 63;
    if (lane == 0) redm[wave] = m;
    __syncthreads();
    m = fmaxf(fmaxf(redm[0], redm[1]), fmaxf(redm[2], redm[3]));
    float s = 0.f;
#pragma unroll
    for (int i = 0; i < 8; i++) {
        v[i] = __expf(v[i] - m);
        s += v[i];
    }
#pragma unroll
    for (int off = 32; off > 0; off >>= 1) s += __shfl_down(s, off, 64);
    if (lane == 0) reds[wave] = s;
    __syncthreads();
    s = reds[0] + reds[1] + reds[2] + reds[3];
    const float inv = 1.0f / s;
#pragma unroll
    for (int i = 0; i < 8; i++) p[t + i * 256] = v[i] * inv;
}

// ---------------------------------------------------------------------------
// ctx[b,t,h*64+c] = sum_q attn[b,h,t,q] * V[b,h,q,c]; V at res col 2D + h*64.
// Causal skip: attn[t,q]==0 for q>t, so K-loop stops at bt+64.
// Writes ctx directly in [B,T,D] layout for the final GEMM.
// ---------------------------------------------------------------------------
__global__ __launch_bounds__(256) void ctx_kernel(const float* __restrict__ attn,
                                                  const float* __restrict__ res,
                                                  float* __restrict__ ctx) {
    const int bh = blockIdx.y;
    const int b = bh >> 4, h = bh & 15;
    const int bt = blockIdx.x * 64;
    const int tid = threadIdx.x;
    const int tx = tid & 15, ty = tid >> 4;
    const float* A = attn + (size_t)bh * T_ * T_;
    const float* Vg = res + (size_t)b * T_ * (3 * D_) + 2 * D_ + h * HD_;
    __shared__ float As[16][65];  // [q][t]
    __shared__ float Vs[16][65];  // [q][c]
    float acc[4][4] = {};
    const int atr = tid >> 2, aq4 = (tid & 3) * 4;   // attn tile: 64 t x 16 q
    const int vq = tid >> 4, vc4 = (tid & 15) * 4;   // V tile: 16 q x 64 c
    const int qend = bt + 64;                        // only q <= t_max needed
    for (int q0 = 0; q0 < qend; q0 += 16) {
        float4 av = *(const float4*)&A[(size_t)(bt + atr) * T_ + q0 + aq4];
        float4 vv = *(const float4*)&Vg[(size_t)(q0 + vq) * (3 * D_) + vc4];
        As[aq4 + 0][atr] = av.x;
        As[aq4 + 1][atr] = av.y;
        As[aq4 + 2][atr] = av.z;
        As[aq4 + 3][atr] = av.w;
        Vs[vq][vc4 + 0] = vv.x; Vs[vq][vc4 + 1] = vv.y;
        Vs[vq][vc4 + 2] = vv.z; Vs[vq][vc4 + 3] = vv.w;
        __syncthreads();
#pragma unroll
        for (int qq = 0; qq < 16; qq++) {
            float a[4], bv[4];
#pragma unroll
            for (int i = 0; i < 4; i++) a[i] = As[qq][ty * 4 + i];
#pragma unroll
            for (int j = 0; j < 4; j++) bv[j] = Vs[qq][tx * 4 + j];
#pragma unroll
            for (int i = 0; i < 4; i++)
#pragma unroll
                for (int j = 0; j < 4; j++) acc[i][j] += a[i] * bv[j];
        }
        __syncthreads();
    }
#pragma unroll
    for (int i = 0; i < 4; i++) {
        *(float4*)&ctx[(size_t)(b * T_ + bt + ty * 4 + i) * D_ + h * HD_ + tx * 4] =
            make_float4(acc[i][0], acc[i][1], acc[i][2], acc[i][3]);
    }
}

// ---------------------------------------------------------------------------
// d_in: X [B,T,D] f32, W_KQV [D,3D] f32, W_out [D,D] f32, mask [T,T] f32
//       (mask recomputed inline: exactly triu(-1e9, k=1)), heads (ignored).
// d_out: out [B,T,D] (4,194,304 f32) then attn [B,H,T,T] (134,217,728 f32).
// d_ws: res [B*T,3D] f32 (48 MB) + ctx [B*T,D] f32 (16 MB) = 64 MB.
// ---------------------------------------------------------------------------
extern "C" void kernel_launch(void* const* d_in, const int* in_sizes, int n_in,
                              void* d_out, int out_size, void* d_ws, size_t ws_size,
                              hipStream_t stream) {
    const float* X = (const float*)d_in[0];
    const float* W_KQV = (const float*)d_in[1];
    const float* W_out = (const float*)d_in[2];
    float* out = (float*)d_out;                              // [B,T,D]
    float* attn = (float*)d_out + (size_t)B_ * T_ * D_;      // [B,H,T,T]
    float* res = (float*)d_ws;                               // [B*T, 3D]
    float* ctx = res + (size_t)B_ * T_ * 3 * D_;             // [B*T, D]

    // 1. res = X @ W_KQV   (M=4096, N=3072, K=1024)
    gemm_tiled<<<dim3((3 * D_) / 64, (B_ * T_) / 64), 256, 0, stream>>>(
        X, W_KQV, res, B_ * T_, 3 * D_, D_);
    // 2. scores = K @ Q^T / 8 + mask  -> attn region (pre-softmax)
    scores_kernel<<<dim3(T_ / 64, T_ / 64, B_ * H_), 256, 0, stream>>>(res, attn);
    // 3. softmax rows in place
    softmax_kernel<<<B_ * H_ * T_, 256, 0, stream>>>(attn);
    // 4. ctx = attn @ V  (causal-skip upper triangle)
    ctx_kernel<<<dim3(T_ / 64, B_ * H_), 256, 0, stream>>>(attn, res, ctx);
    // 5. out = ctx @ W_out (M=4096, N=1024, K=1024)
    gemm_tiled<<<dim3(D_ / 64, (B_ * T_) / 64), 256, 0, stream>>>(
        ctx, W_out, out, B_ * T_, D_, D_);
}

// Round 2
// 874.809 us; speedup vs baseline: 2.2300x; 2.2300x over previous
//
#include <hip/hip_runtime.h>
#include <cstddef>

constexpr int B_ = 2, T_ = 2048, D_ = 1024, H_ = 16;

typedef __attribute__((ext_vector_type(8))) short short8;
typedef __attribute__((ext_vector_type(4))) float floatx4;

__device__ inline unsigned short f2bf(float f) {
    union { float f; unsigned int u; } v; v.f = f;
    unsigned int r = v.u + 0x7fffu + ((v.u >> 16) & 1u);
    return (unsigned short)(r >> 16);
}

#define GLD_LDS16(gptr, ldsptr)                                                        \
    __builtin_amdgcn_global_load_lds(                                                  \
        (const __attribute__((address_space(1))) void*)(gptr),                         \
        (__attribute__((address_space(3))) void*)(ldsptr), 16, 0, 0)

// ---------------------------------------------------------------------------
// cast fp32 -> bf16, 8 elems/thread
// ---------------------------------------------------------------------------
__global__ __launch_bounds__(256) void cast_bf16(const float* __restrict__ in,
                                                 unsigned short* __restrict__ out) {
    int idx = (blockIdx.x * 256 + threadIdx.x) * 8;
    float4 a = *(const float4*)(in + idx);
    float4 b = *(const float4*)(in + idx + 4);
    unsigned short tmp[8] = {f2bf(a.x), f2bf(a.y), f2bf(a.z), f2bf(a.w),
                             f2bf(b.x), f2bf(b.y), f2bf(b.z), f2bf(b.w)};
    *(uint4*)(out + idx) = *(const uint4*)tmp;
}

// ---------------------------------------------------------------------------
// W [K,N] fp32 -> Wt [N,K] bf16 (64x64 tiles)
// ---------------------------------------------------------------------------
__global__ __launch_bounds__(256) void transpose_cast(const float* __restrict__ W,
                                                      unsigned short* __restrict__ Wt,
                                                      int K, int N) {
    const int k0 = blockIdx.y * 64, n0 = blockIdx.x * 64;
    __shared__ float t[64][65];
    const int tid = threadIdx.x;
    const int row = tid >> 4, c4 = (tid & 15) * 4;
#pragma unroll
    for (int r = 0; r < 4; r++) {
        float4 v = *(const float4*)&W[(size_t)(k0 + row + r * 16) * N + n0 + c4];
        t[row + r * 16][c4 + 0] = v.x; t[row + r * 16][c4 + 1] = v.y;
        t[row + r * 16][c4 + 2] = v.z; t[row + r * 16][c4 + 3] = v.w;
    }
    __syncthreads();
    const int n = tid >> 2, ks = (tid & 3) * 16;
    unsigned short o[16];
#pragma unroll
    for (int i = 0; i < 16; i++) o[i] = f2bf(t[ks + i][n]);
    unsigned short* dst = Wt + (size_t)(n0 + n) * K + k0 + ks;
    *(uint4*)dst = ((const uint4*)o)[0];
    *(uint4*)(dst + 8) = ((const uint4*)o)[1];
}

// ---------------------------------------------------------------------------
// bf16 MFMA GEMM, bt-form: C[M,N] = A[M,K] * Bt[N,K]^T. 128x128 tile,
// 256 thr = 4 waves (2x2 of 64x64), BK=32, global_load_lds width-16 staging.
// ---------------------------------------------------------------------------
template <typename CT>
__global__ __launch_bounds__(256) void gemm_bt(const unsigned short* __restrict__ A,
                                               const unsigned short* __restrict__ Bt,
                                               CT* __restrict__ C, int M, int N, int K) {
    __shared__ unsigned short As[128 * 32];
    __shared__ unsigned short Bs[128 * 32];
    const int tid = threadIdx.x;
    const int lane = tid & 63, wave = tid >> 6;
    const int quad = lane >> 4, l16 = lane & 15;
    const int wr = wave >> 1, wc = wave & 1;
    const size_t bm = (size_t)blockIdx.y * 128, bn = (size_t)blockIdx.x * 128;
    const int r0 = tid >> 2, kc0 = (tid & 3) * 8;
    const unsigned short* Ap = A + bm * K;
    const unsigned short* Bp = Bt + bn * K;
    floatx4 acc[4][4] = {};
    for (int k0 = 0; k0 < K; k0 += 32) {
        GLD_LDS16(Ap + (size_t)r0 * K + k0 + kc0, &As[tid * 8]);
        GLD_LDS16(Ap + (size_t)(r0 + 64) * K + k0 + kc0, &As[(tid + 256) * 8]);
        GLD_LDS16(Bp + (size_t)r0 * K + k0 + kc0, &Bs[tid * 8]);
        GLD_LDS16(Bp + (size_t)(r0 + 64) * K + k0 + kc0, &Bs[(tid + 256) * 8]);
        __syncthreads();
        short8 af[4], bf[4];
#pragma unroll
        for (int i = 0; i < 4; i++)
            af[i] = *(const short8*)&As[(wr * 64 + i * 16 + l16) * 32 + quad * 8];
#pragma unroll
        for (int j = 0; j < 4; j++)
            bf[j] = *(const short8*)&Bs[(wc * 64 + j * 16 + l16) * 32 + quad * 8];
#pragma unroll
        for (int i = 0; i < 4; i++)
#pragma unroll
            for (int j = 0; j < 4; j++)
                acc[i][j] = __builtin_amdgcn_mfma_f32_16x16x32_bf16(af[i], bf[j], acc[i][j], 0, 0, 0);
        __syncthreads();
    }
#pragma unroll
    for (int i = 0; i < 4; i++) {
        size_t row0 = bm + wr * 64 + i * 16 + quad * 4;
#pragma unroll
        for (int j = 0; j < 4; j++) {
            size_t col = bn + wc * 64 + j * 16 + l16;
#pragma unroll
            for (int r = 0; r < 4; r++) {
                if constexpr (sizeof(CT) == 2)
                    C[(row0 + r) * N + col] = (CT)f2bf(acc[i][j][r]);
                else
                    C[(row0 + r) * N + col] = acc[i][j][r];
            }
        }
    }
}

// ---------------------------------------------------------------------------
// scores: S[k,q] = K.Q^T/8 + causal mask. 128x128 tile per (b,h) block pair.
// Fully-masked blocks (bq > bk) write ZEROS (final attn value) directly.
// ---------------------------------------------------------------------------
__global__ __launch_bounds__(256) void scores_mfma(const unsigned short* __restrict__ resb,
                                                   float* __restrict__ attn) {
    const int bh = blockIdx.z, b = bh >> 4, h = bh & 15;
    const int bk = blockIdx.y * 128, bq = blockIdx.x * 128;
    float* S = attn + (size_t)bh * T_ * T_;
    const int tid = threadIdx.x;
    if (bq > bk) {
        const float4 z = make_float4(0.f, 0.f, 0.f, 0.f);
#pragma unroll
        for (int i = 0; i < 16; i++) {
            int idx = tid + i * 256;
            int row = idx >> 5, c4 = (idx & 31) * 4;
            *(float4*)&S[(size_t)(bk + row) * T_ + bq + c4] = z;
        }
        return;
    }
    __shared__ unsigned short Ks[128 * 64];
    __shared__ unsigned short Qs[128 * 64];
    const unsigned short* Kg = resb + (size_t)b * T_ * (3 * D_) + h * 64;
    const unsigned short* Qg = Kg + D_;
    const int row = tid >> 3, dc = (tid & 7) * 8;
#pragma unroll
    for (int r = 0; r < 4; r++) {
        GLD_LDS16(Kg + (size_t)(bk + row + r * 32) * (3 * D_) + dc, &Ks[(tid + r * 256) * 8]);
        GLD_LDS16(Qg + (size_t)(bq + row + r * 32) * (3 * D_) + dc, &Qs[(tid + r * 256) * 8]);
    }
    __syncthreads();
    const int lane = tid & 63, wave = tid >> 6;
    const int quad = lane >> 4, l16 = lane & 15;
    const int wr = wave >> 1, wc = wave & 1;
    floatx4 acc[4][4] = {};
#pragma unroll
    for (int ks = 0; ks < 2; ks++) {
        short8 af[4], bf[4];
#pragma unroll
        for (int i = 0; i < 4; i++)
            af[i] = *(const short8*)&Ks[(wr * 64 + i * 16 + l16) * 64 + ks * 32 + quad * 8];
#pragma unroll
        for (int j = 0; j < 4; j++)
            bf[j] = *(const short8*)&Qs[(wc * 64 + j * 16 + l16) * 64 + ks * 32 + quad * 8];
#pragma unroll
        for (int i = 0; i < 4; i++)
#pragma unroll
            for (int j = 0; j < 4; j++)
                acc[i][j] = __builtin_amdgcn_mfma_f32_16x16x32_bf16(af[i], bf[j], acc[i][j], 0, 0, 0);
    }
#pragma unroll
    for (int i = 0; i < 4; i++) {
        int k0r = bk + wr * 64 + i * 16 + quad * 4;
#pragma unroll
        for (int j = 0; j < 4; j++) {
            int q = bq + wc * 64 + j * 16 + l16;
#pragma unroll
            for (int r = 0; r < 4; r++) {
                int k = k0r + r;
                S[(size_t)k * T_ + q] = (q > k) ? -1e9f : acc[i][j][r] * 0.125f;
            }
        }
    }
}

// ---------------------------------------------------------------------------
// causal softmax: row k only has q in [0, L), L = round-up-128(k+1);
// beyond L the zeros were already written by scores_mfma.
// ---------------------------------------------------------------------------
__global__ __launch_bounds__(256) void softmax_causal(float* __restrict__ attn) {
    const size_t row = blockIdx.x;
    const int k = (int)(row & (T_ - 1));
    const int L = ((k >> 7) + 1) << 7;
    float* p = attn + row * (size_t)T_;
    const int t = threadIdx.x;
    float v[8];
    float m = -3.0e38f;
#pragma unroll
    for (int i = 0; i < 8; i++) {
        int q = t + i * 256;
        v[i] = (q < L) ? p[q] : -1e9f;
        m = fmaxf(m, v[i]);
    }
#pragma unroll
    for (int off = 32; off > 0; off >>= 1) m = fmaxf(m, __shfl_down(m, off, 64));
    __shared__ float redm[4], reds[4];
    const int wave = t >> 6, lane = t & 63;
    if (lane == 0) redm[wave] = m;
    __syncthreads();
    m = fmaxf(fmaxf(redm[0], redm[1]), fmaxf(redm[2], redm[3]));
    float s = 0.f;
#pragma unroll
    for (int i = 0; i < 8; i++) {
        v[i] = __expf(v[i] - m);
        s += v[i];
    }
#pragma unroll
    for (int off = 32; off > 0; off >>= 1) s += __shfl_down(s, off, 64);
    if (lane == 0) reds[wave] = s;
    __syncthreads();
    s = reds[0] + reds[1] + reds[2] + reds[3];
    const float inv = 1.0f / s;
#pragma unroll
    for (int i = 0; i < 8; i++) {
        int q = t + i * 256;
        if (q < L) p[q] = v[i] * inv;
    }
}

// ---------------------------------------------------------------------------
// V inside res (bf16) -> Vt[bh][c][q] for k-contiguous MFMA B-fragments
// ---------------------------------------------------------------------------
__global__ __launch_bounds__(256) void transpose_v(const unsigned short* __restrict__ resb,
                                                   unsigned short* __restrict__ Vt) {
    const int bh = blockIdx.y, b = bh >> 4, h = bh & 15;
    const int q0 = blockIdx.x * 64;
    __shared__ unsigned short t[64][66];
    const int tid = threadIdx.x;
    const unsigned short* Vg = resb + (size_t)b * T_ * (3 * D_) + 2 * D_ + h * 64;
    const int q = tid >> 3, c8 = (tid & 7) * 8;
#pragma unroll
    for (int r = 0; r < 2; r++) {
        int qq = q + r * 32;
        short8 v = *(const short8*)(Vg + (size_t)(q0 + qq) * (3 * D_) + c8);
#pragma unroll
        for (int i = 0; i < 8; i++) t[qq][c8 + i] = (unsigned short)v[i];
    }
    __syncthreads();
    const int c = tid >> 2, qs = (tid & 3) * 16;
    unsigned short o[16];
#pragma unroll
    for (int i = 0; i < 16; i++) o[i] = t[qs + i][c];
    unsigned short* dst = Vt + ((size_t)bh * 64 + c) * T_ + q0 + qs;
    *(uint4*)dst = ((const uint4*)o)[0];
    *(uint4*)(dst + 8) = ((const uint4*)o)[1];
}

// ---------------------------------------------------------------------------
// ctx[b,t,h*64+c] = sum_q attn[t,q] * V[q,c]; attn fp32 -> bf16 inline stage,
// Vt staged via global_load_lds. 128t x 64c per block, causal K-loop skip.
// ---------------------------------------------------------------------------
__global__ __launch_bounds__(256) void ctx_mfma(const float* __restrict__ attn,
                                                const unsigned short* __restrict__ Vt,
                                                unsigned short* __restrict__ ctxb) {
    const int bh = blockIdx.y, b = bh >> 4, h = bh & 15;
    const int bt = blockIdx.x * 128;
    const float* Ag = attn + (size_t)bh * T_ * T_;
    const unsigned short* Bg = Vt + (size_t)bh * 64 * T_;
    __shared__ unsigned short As[128 * 40];  // rows padded to 40 (80B) for bank spread
    __shared__ unsigned short Bs[64 * 32];
    const int tid = threadIdx.x;
    const int lane = tid & 63, wave = tid >> 6;
    const int quad = lane >> 4, l16 = lane & 15;
    const int wr = wave >> 1, wc = wave & 1;
    const int arow = tid >> 1, aq = (tid & 1) * 16;
    const int brow = tid >> 2, bq8 = (tid & 3) * 8;
    floatx4 acc[4][2] = {};
    const int qend = bt + 128;
    for (int q0 = 0; q0 < qend; q0 += 32) {
        const float* src = Ag + (size_t)(bt + arow) * T_ + q0 + aq;
        float4 v0 = *(const float4*)src;
        float4 v1 = *(const float4*)(src + 4);
        float4 v2 = *(const float4*)(src + 8);
        float4 v3 = *(const float4*)(src + 12);
        unsigned short tmp[16] = {f2bf(v0.x), f2bf(v0.y), f2bf(v0.z), f2bf(v0.w),
                                  f2bf(v1.x), f2bf(v1.y), f2bf(v1.z), f2bf(v1.w),
                                  f2bf(v2.x), f2bf(v2.y), f2bf(v2.z), f2bf(v2.w),
                                  f2bf(v3.x), f2bf(v3.y), f2bf(v3.z), f2bf(v3.w)};
        *(uint4*)&As[arow * 40 + aq] = ((const uint4*)tmp)[0];
        *(uint4*)&As[arow * 40 + aq + 8] = ((const uint4*)tmp)[1];
        GLD_LDS16(Bg + (size_t)brow * T_ + q0 + bq8, &Bs[tid * 8]);
        __syncthreads();
        short8 af[4], bf[2];
#pragma unroll
        for (int i = 0; i < 4; i++)
            af[i] = *(const short8*)&As[(wr * 64 + i * 16 + l16) * 40 + quad * 8];
#pragma unroll
        for (int j = 0; j < 2; j++)
            bf[j] = *(const short8*)&Bs[(wc * 32 + j * 16 + l16) * 32 + quad * 8];
#pragma unroll
        for (int i = 0; i < 4; i++)
#pragma unroll
            for (int j = 0; j < 2; j++)
                acc[i][j] = __builtin_amdgcn_mfma_f32_16x16x32_bf16(af[i], bf[j], acc[i][j], 0, 0, 0);
        __syncthreads();
    }
#pragma unroll
    for (int i = 0; i < 4; i++) {
        size_t t0 = (size_t)bt + wr * 64 + i * 16 + quad * 4;
#pragma unroll
        for (int j = 0; j < 2; j++) {
            int c = wc * 32 + j * 16 + l16;
#pragma unroll
            for (int r = 0; r < 4; r++)
                ctxb[((size_t)b * T_ + t0 + r) * D_ + h * 64 + c] = f2bf(acc[i][j][r]);
        }
    }
}

// ---------------------------------------------------------------------------
// ws layout (bytes): Xb 8M | Wt 6M | Wot 2M | resb 24M | Vt 8M | ctxb 8M = 56M
// ---------------------------------------------------------------------------
extern "C" void kernel_launch(void* const* d_in, const int* in_sizes, int n_in,
                              void* d_out, int out_size, void* d_ws, size_t ws_size,
                              hipStream_t stream) {
    const float* X = (const float*)d_in[0];
    const float* W_KQV = (const float*)d_in[1];
    const float* W_out = (const float*)d_in[2];
    float* out = (float*)d_out;
    float* attn = (float*)d_out + (size_t)B_ * T_ * D_;

    char* ws = (char*)d_ws;
    unsigned short* Xb = (unsigned short*)ws;                       // [4096,1024]
    unsigned short* Wt = (unsigned short*)(ws + (8u << 20));        // [3072,1024]
    unsigned short* Wot = (unsigned short*)(ws + (14u << 20));      // [1024,1024]
    unsigned short* resb = (unsigned short*)(ws + (16u << 20));     // [4096,3072]
    unsigned short* Vt = (unsigned short*)(ws + (40u << 20));       // [32,64,2048]
    unsigned short* ctxb = (unsigned short*)(ws + (48u << 20));     // [4096,1024]

    cast_bf16<<<(B_ * T_ * D_) / (8 * 256), 256, 0, stream>>>(X, Xb);
    transpose_cast<<<dim3((3 * D_) / 64, D_ / 64), 256, 0, stream>>>(W_KQV, Wt, D_, 3 * D_);
    transpose_cast<<<dim3(D_ / 64, D_ / 64), 256, 0, stream>>>(W_out, Wot, D_, D_);

    gemm_bt<unsigned short><<<dim3((3 * D_) / 128, (B_ * T_) / 128), 256, 0, stream>>>(
        Xb, Wt, resb, B_ * T_, 3 * D_, D_);

    transpose_v<<<dim3(T_ / 64, B_ * H_), 256, 0, stream>>>(resb, Vt);
    scores_mfma<<<dim3(T_ / 128, T_ / 128, B_ * H_), 256, 0, stream>>>(resb, attn);
    softmax_causal<<<B_ * H_ * T_, 256, 0, stream>>>(attn);
    ctx_mfma<<<dim3(T_ / 128, B_ * H_), 256, 0, stream>>>(attn, Vt, ctxb);

    gemm_bt<float><<<dim3(D_ / 128, (B_ * T_) / 128), 256, 0, stream>>>(
        ctxb, Wot, out, B_ * T_, D_, D_);
}

// Round 3
// 805.622 us; speedup vs baseline: 2.4215x; 1.0859x over previous
//
#include <hip/hip_runtime.h>
#include <cstddef>

constexpr int B_ = 2, T_ = 2048, D_ = 1024, H_ = 16;

typedef __attribute__((ext_vector_type(8))) short short8;
typedef __attribute__((ext_vector_type(4))) float floatx4;

__device__ inline unsigned short f2bf(float f) {
    union { float f; unsigned int u; } v; v.f = f;
    unsigned int r = v.u + 0x7fffu + ((v.u >> 16) & 1u);
    return (unsigned short)(r >> 16);
}

#define GLD_LDS16(gptr, ldsptr)                                                        \
    __builtin_amdgcn_global_load_lds(                                                  \
        (const __attribute__((address_space(1))) void*)(gptr),                         \
        (__attribute__((address_space(3))) void*)(ldsptr), 16, 0, 0)

// ---------------------------------------------------------------------------
// cast fp32 -> bf16, 8 elems/thread
// ---------------------------------------------------------------------------
__global__ __launch_bounds__(256) void cast_bf16(const float* __restrict__ in,
                                                 unsigned short* __restrict__ out) {
    int idx = (blockIdx.x * 256 + threadIdx.x) * 8;
    float4 a = *(const float4*)(in + idx);
    float4 b = *(const float4*)(in + idx + 4);
    unsigned short tmp[8] = {f2bf(a.x), f2bf(a.y), f2bf(a.z), f2bf(a.w),
                             f2bf(b.x), f2bf(b.y), f2bf(b.z), f2bf(b.w)};
    *(uint4*)(out + idx) = *(const uint4*)tmp;
}

// ---------------------------------------------------------------------------
// W [K,N] fp32 -> Wt [N,K] bf16 (64x64 tiles)
// ---------------------------------------------------------------------------
__global__ __launch_bounds__(256) void transpose_cast(const float* __restrict__ W,
                                                      unsigned short* __restrict__ Wt,
                                                      int K, int N) {
    const int k0 = blockIdx.y * 64, n0 = blockIdx.x * 64;
    __shared__ float t[64][65];
    const int tid = threadIdx.x;
    const int row = tid >> 4, c4 = (tid & 15) * 4;
#pragma unroll
    for (int r = 0; r < 4; r++) {
        float4 v = *(const float4*)&W[(size_t)(k0 + row + r * 16) * N + n0 + c4];
        t[row + r * 16][c4 + 0] = v.x; t[row + r * 16][c4 + 1] = v.y;
        t[row + r * 16][c4 + 2] = v.z; t[row + r * 16][c4 + 3] = v.w;
    }
    __syncthreads();
    const int n = tid >> 2, ks = (tid & 3) * 16;
    unsigned short o[16];
#pragma unroll
    for (int i = 0; i < 16; i++) o[i] = f2bf(t[ks + i][n]);
    unsigned short* dst = Wt + (size_t)(n0 + n) * K + k0 + ks;
    *(uint4*)dst = ((const uint4*)o)[0];
    *(uint4*)(dst + 8) = ((const uint4*)o)[1];
}

// ---------------------------------------------------------------------------
// bf16 MFMA GEMM, bt-form: C[M,N] = A[M,K]*Bt[N,K]^T. 128x128 tile, BK=64,
// XOR-swizzled LDS (chunk c of row r at c^(r&7)) -> conflict-free ds_read_b128.
// ---------------------------------------------------------------------------
template <typename CT>
__global__ __launch_bounds__(256, 2) void gemm_bt(const unsigned short* __restrict__ A,
                                                  const unsigned short* __restrict__ Bt,
                                                  CT* __restrict__ C, int M, int N, int K) {
    __shared__ unsigned short As[128 * 64];
    __shared__ unsigned short Bs[128 * 64];
    const int tid = threadIdx.x;
    const int lane = tid & 63, wave = tid >> 6;
    const int quad = lane >> 4, l16 = lane & 15;
    const int wr = wave >> 1, wc = wave & 1;
    const size_t bm = (size_t)blockIdx.y * 128, bn = (size_t)blockIdx.x * 128;
    const unsigned short* Ap = A + bm * K;
    const unsigned short* Bp = Bt + bn * K;
    const int srow = tid >> 3, sc = tid & 7;
    floatx4 acc[4][4] = {};
    for (int k0 = 0; k0 < K; k0 += 64) {
#pragma unroll
        for (int it = 0; it < 4; it++) {
            int rr = srow + it * 32;
            int soff = k0 + ((sc ^ (rr & 7)) << 3);
            GLD_LDS16(Ap + (size_t)rr * K + soff, &As[(tid + it * 256) * 8]);
            GLD_LDS16(Bp + (size_t)rr * K + soff, &Bs[(tid + it * 256) * 8]);
        }
        __syncthreads();
#pragma unroll
        for (int ks = 0; ks < 2; ks++) {
            short8 af[4], bf[4];
#pragma unroll
            for (int i = 0; i < 4; i++) {
                int row = wr * 64 + i * 16 + l16, cf = ks * 4 + quad;
                af[i] = *(const short8*)&As[row * 64 + ((cf ^ (row & 7)) << 3)];
            }
#pragma unroll
            for (int j = 0; j < 4; j++) {
                int row = wc * 64 + j * 16 + l16, cf = ks * 4 + quad;
                bf[j] = *(const short8*)&Bs[row * 64 + ((cf ^ (row & 7)) << 3)];
            }
#pragma unroll
            for (int i = 0; i < 4; i++)
#pragma unroll
                for (int j = 0; j < 4; j++)
                    acc[i][j] = __builtin_amdgcn_mfma_f32_16x16x32_bf16(af[i], bf[j], acc[i][j], 0, 0, 0);
        }
        __syncthreads();
    }
#pragma unroll
    for (int i = 0; i < 4; i++) {
        size_t row0 = bm + wr * 64 + i * 16 + quad * 4;
#pragma unroll
        for (int j = 0; j < 4; j++) {
            size_t col = bn + wc * 64 + j * 16 + l16;
#pragma unroll
            for (int r = 0; r < 4; r++) {
                if constexpr (sizeof(CT) == 2)
                    C[(row0 + r) * N + col] = (CT)f2bf(acc[i][j][r]);
                else
                    C[(row0 + r) * N + col] = acc[i][j][r];
            }
        }
    }
}

// ---------------------------------------------------------------------------
// V inside res (bf16) -> Vt[bh][c][q] for k-contiguous MFMA B-fragments
// ---------------------------------------------------------------------------
__global__ __launch_bounds__(256) void transpose_v(const unsigned short* __restrict__ resb,
                                                   unsigned short* __restrict__ Vt) {
    const int bh = blockIdx.y, b = bh >> 4, h = bh & 15;
    const int q0 = blockIdx.x * 64;
    __shared__ unsigned short t[64][66];
    const int tid = threadIdx.x;
    const unsigned short* Vg = resb + (size_t)b * T_ * (3 * D_) + 2 * D_ + h * 64;
    const int q = tid >> 3, c8 = (tid & 7) * 8;
#pragma unroll
    for (int r = 0; r < 2; r++) {
        int qq = q + r * 32;
        short8 v = *(const short8*)(Vg + (size_t)(q0 + qq) * (3 * D_) + c8);
#pragma unroll
        for (int i = 0; i < 8; i++) t[qq][c8 + i] = (unsigned short)v[i];
    }
    __syncthreads();
    const int c = tid >> 2, qs = (tid & 3) * 16;
    unsigned short o[16];
#pragma unroll
    for (int i = 0; i < 16; i++) o[i] = t[qs + i][c];
    unsigned short* dst = Vt + ((size_t)bh * 64 + c) * T_ + q0 + qs;
    *(uint4*)dst = ((const uint4*)o)[0];
    *(uint4*)(dst + 8) = ((const uint4*)o)[1];
}

// ---------------------------------------------------------------------------
// Fused attention: per (bh, 128-row k-tile) block.
//   pass A: stream q-tiles, QK^T MFMA, online row (m,l).
//   pass B: re-stream, recompute S, write final attn = exp(s-m)/l (plus
//           diag-mask zeros and upper zero-fill), P->LDS (A-layout), PV MFMA
//           accumulating ctx in registers; epilogue writes ctxb bf16.
// LDS: KV = Ks[128][64] swizzled  (later Vs[64][132] padded)
//      QP = Qs[128][64] swizzled  (later Ps[128][132] padded)
// ---------------------------------------------------------------------------
__global__ __launch_bounds__(256, 2) void attn_fused(const unsigned short* __restrict__ resb,
                                                     const unsigned short* __restrict__ Vt,
                                                     float* __restrict__ attn,
                                                     unsigned short* __restrict__ ctxb) {
    const int bh = blockIdx.y, b = bh >> 4, h = bh & 15;
    const int kt = 15 - (int)blockIdx.x;  // heavy blocks first
    const int k0 = kt * 128;
    float* S = attn + (size_t)bh * T_ * T_;

    __shared__ char smem[53760];
    unsigned short* KV = (unsigned short*)smem;             // 16896 B
    unsigned short* QP = (unsigned short*)(smem + 16896);   // 33792 B
    float* mpart = (float*)(smem + 16896 + 33792);          // [2][128]
    float* lpart = mpart + 256;                             // [2][128]
    float* mfin = lpart + 256;                              // [128]
    float* linv = mfin + 128;                               // [128]

    const int tid = threadIdx.x;
    const int lane = tid & 63, wave = tid >> 6;
    const int quad = lane >> 4, l16 = lane & 15;
    const int wr = wave >> 1, wc = wave & 1;

    const unsigned short* Kg = resb + (size_t)b * T_ * (3 * D_) + h * 64;
    const unsigned short* Qg = Kg + D_;
    const unsigned short* Vg = Vt + (size_t)bh * 64 * T_;

    // ---- zero-fill attn cols >= (kt+1)*128 for these 128 rows ----
    {
        const int qz0 = (kt + 1) * 128, ZW = T_ - qz0;
        const float4 z = make_float4(0.f, 0.f, 0.f, 0.f);
        for (int row = wave; row < 128; row += 4)
            for (int c = lane * 4; c < ZW; c += 256)
                *(float4*)&S[(size_t)(k0 + row) * T_ + qz0 + c] = z;
    }

    // ---- stage K rows once (swizzled), hoist K fragments to registers ----
    const int srow = tid >> 3, sc = tid & 7;
#pragma unroll
    for (int it = 0; it < 4; it++) {
        int rr = srow + it * 32;
        GLD_LDS16(Kg + (size_t)(k0 + rr) * (3 * D_) + ((sc ^ (rr & 7)) << 3),
                  &KV[(tid + it * 256) * 8]);
    }
    __syncthreads();
    short8 af_k[4][2];
#pragma unroll
    for (int i = 0; i < 4; i++)
#pragma unroll
        for (int ks = 0; ks < 2; ks++) {
            int row = wr * 64 + i * 16 + l16, cf = ks * 4 + quad;
            af_k[i][ks] = *(const short8*)&KV[row * 64 + ((cf ^ (row & 7)) << 3)];
        }
    __syncthreads();  // KV region now free for Vs

    // ================= pass A: row max + sum of exp =================
    float m_run[4][4], l_run[4][4];
#pragma unroll
    for (int i = 0; i < 4; i++)
#pragma unroll
        for (int r = 0; r < 4; r++) { m_run[i][r] = -3.0e38f; l_run[i][r] = 0.f; }

    for (int qt = 0; qt <= kt; qt++) {
        const int q0 = qt * 128;
#pragma unroll
        for (int it = 0; it < 4; it++) {
            int rr = srow + it * 32;
            GLD_LDS16(Qg + (size_t)(q0 + rr) * (3 * D_) + ((sc ^ (rr & 7)) << 3),
                      &QP[(tid + it * 256) * 8]);
        }
        __syncthreads();
        short8 bf[4][2];
#pragma unroll
        for (int j = 0; j < 4; j++)
#pragma unroll
            for (int ks = 0; ks < 2; ks++) {
                int row = wc * 64 + j * 16 + l16, cf = ks * 4 + quad;
                bf[j][ks] = *(const short8*)&QP[row * 64 + ((cf ^ (row & 7)) << 3)];
            }
        __syncthreads();  // Qs consumed (regs); next iter may overwrite
        floatx4 acc[4][4] = {};
#pragma unroll
        for (int ks = 0; ks < 2; ks++)
#pragma unroll
            for (int i = 0; i < 4; i++)
#pragma unroll
                for (int j = 0; j < 4; j++)
                    acc[i][j] = __builtin_amdgcn_mfma_f32_16x16x32_bf16(af_k[i][ks], bf[j][ks], acc[i][j], 0, 0, 0);
        const bool dm = (qt == kt);
#pragma unroll
        for (int i = 0; i < 4; i++)
#pragma unroll
            for (int r = 0; r < 4; r++) {
                const int krow = wr * 64 + i * 16 + quad * 4 + r;
                float vv[4];
#pragma unroll
                for (int j = 0; j < 4; j++) {
                    int ql = wc * 64 + j * 16 + l16;
                    float s = acc[i][j][r] * 0.125f;
                    vv[j] = (dm && ql > krow) ? -3.0e38f : s;
                }
                float mt = fmaxf(fmaxf(vv[0], vv[1]), fmaxf(vv[2], vv[3]));
#pragma unroll
                for (int msk = 1; msk < 16; msk <<= 1)
                    mt = fmaxf(mt, __shfl_xor(mt, msk, 64));
                float mn = fmaxf(m_run[i][r], mt);
                float corr = __expf(m_run[i][r] - mn);
                float lt = __expf(vv[0] - mn) + __expf(vv[1] - mn) +
                           __expf(vv[2] - mn) + __expf(vv[3] - mn);
                l_run[i][r] = l_run[i][r] * corr + lt;  // per-lane partial over l16
                m_run[i][r] = mn;
            }
    }
    // reduce l over 16 lanes, merge the two wc column-halves
#pragma unroll
    for (int i = 0; i < 4; i++)
#pragma unroll
        for (int r = 0; r < 4; r++) {
            float lv = l_run[i][r];
#pragma unroll
            for (int msk = 1; msk < 16; msk <<= 1) lv += __shfl_xor(lv, msk, 64);
            if (l16 == 0) {
                int row = wr * 64 + i * 16 + quad * 4 + r;
                mpart[wc * 128 + row] = m_run[i][r];
                lpart[wc * 128 + row] = lv;
            }
        }
    __syncthreads();
    if (tid < 128) {
        float m0 = mpart[tid], m1 = mpart[128 + tid];
        float m = fmaxf(m0, m1);
        float l = lpart[tid] * __expf(m0 - m) + lpart[128 + tid] * __expf(m1 - m);
        mfin[tid] = m;
        linv[tid] = 1.0f / l;
    }
    __syncthreads();

    // ================= pass B: write attn, accumulate ctx =================
    floatx4 cacc[4][2] = {};
    for (int qt = 0; qt <= kt; qt++) {
        const int q0 = qt * 128;
#pragma unroll
        for (int it = 0; it < 4; it++) {
            int rr = srow + it * 32;
            GLD_LDS16(Qg + (size_t)(q0 + rr) * (3 * D_) + ((sc ^ (rr & 7)) << 3),
                      &QP[(tid + it * 256) * 8]);
        }
        // stage V tile [64 c][128 q] padded to stride 132 (manual b128 writes)
#pragma unroll
        for (int it = 0; it < 4; it++) {
            int ci = tid + it * 256;
            int row = ci >> 4, ch = ci & 15;
            short8 v = *(const short8*)&Vg[(size_t)row * T_ + q0 + ch * 8];
            *(short8*)&KV[row * 132 + ch * 8] = v;
        }
        __syncthreads();
        short8 bf[4][2];
#pragma unroll
        for (int j = 0; j < 4; j++)
#pragma unroll
            for (int ks = 0; ks < 2; ks++) {
                int row = wc * 64 + j * 16 + l16, cf = ks * 4 + quad;
                bf[j][ks] = *(const short8*)&QP[row * 64 + ((cf ^ (row & 7)) << 3)];
            }
        floatx4 acc[4][4] = {};
#pragma unroll
        for (int ks = 0; ks < 2; ks++)
#pragma unroll
            for (int i = 0; i < 4; i++)
#pragma unroll
                for (int j = 0; j < 4; j++)
                    acc[i][j] = __builtin_amdgcn_mfma_f32_16x16x32_bf16(af_k[i][ks], bf[j][ks], acc[i][j], 0, 0, 0);
        __syncthreads();  // Qs dead; about to overwrite region with Ps
        const bool dm = (qt == kt);
#pragma unroll
        for (int i = 0; i < 4; i++)
#pragma unroll
            for (int r = 0; r < 4; r++) {
                const int krow = wr * 64 + i * 16 + quad * 4 + r;
                const float mv = mfin[krow], li = linv[krow];
#pragma unroll
                for (int j = 0; j < 4; j++) {
                    int ql = wc * 64 + j * 16 + l16;
                    float p = __expf(acc[i][j][r] * 0.125f - mv) * li;
                    if (dm && ql > krow) p = 0.f;
                    S[(size_t)(k0 + krow) * T_ + q0 + ql] = p;
                    QP[krow * 132 + ql] = f2bf(p);
                }
            }
        __syncthreads();  // Ps + Vs ready
#pragma unroll
        for (int ks2 = 0; ks2 < 4; ks2++) {
            short8 ap[4], bv[2];
#pragma unroll
            for (int i = 0; i < 4; i++)
                ap[i] = *(const short8*)&QP[(wr * 64 + i * 16 + l16) * 132 + ks2 * 32 + quad * 8];
#pragma unroll
            for (int j2 = 0; j2 < 2; j2++)
                bv[j2] = *(const short8*)&KV[(wc * 32 + j2 * 16 + l16) * 132 + ks2 * 32 + quad * 8];
#pragma unroll
            for (int i = 0; i < 4; i++)
#pragma unroll
                for (int j2 = 0; j2 < 2; j2++)
                    cacc[i][j2] = __builtin_amdgcn_mfma_f32_16x16x32_bf16(ap[i], bv[j2], cacc[i][j2], 0, 0, 0);
        }
        __syncthreads();  // Ps/Vs consumed before next staging
    }
    // ctx epilogue (bf16, [B,T,D] layout)
#pragma unroll
    for (int i = 0; i < 4; i++) {
        size_t t0 = (size_t)k0 + wr * 64 + i * 16 + quad * 4;
#pragma unroll
        for (int j2 = 0; j2 < 2; j2++) {
            int c = wc * 32 + j2 * 16 + l16;
#pragma unroll
            for (int r = 0; r < 4; r++)
                ctxb[((size_t)b * T_ + t0 + r) * D_ + h * 64 + c] = f2bf(cacc[i][j2][r]);
        }
    }
}

// ---------------------------------------------------------------------------
// ws layout (bytes): Xb 8M | Wt 6M | Wot 2M | resb 24M | Vt 8M | ctxb 8M = 56M
// ---------------------------------------------------------------------------
extern "C" void kernel_launch(void* const* d_in, const int* in_sizes, int n_in,
                              void* d_out, int out_size, void* d_ws, size_t ws_size,
                              hipStream_t stream) {
    const float* X = (const float*)d_in[0];
    const float* W_KQV = (const float*)d_in[1];
    const float* W_out = (const float*)d_in[2];
    float* out = (float*)d_out;
    float* attn = (float*)d_out + (size_t)B_ * T_ * D_;

    char* ws = (char*)d_ws;
    unsigned short* Xb = (unsigned short*)ws;                    // [4096,1024]
    unsigned short* Wt = (unsigned short*)(ws + (8u << 20));     // [3072,1024]
    unsigned short* Wot = (unsigned short*)(ws + (14u << 20));   // [1024,1024]
    unsigned short* resb = (unsigned short*)(ws + (16u << 20));  // [4096,3072]
    unsigned short* Vt = (unsigned short*)(ws + (40u << 20));    // [32,64,2048]
    unsigned short* ctxb = (unsigned short*)(ws + (48u << 20));  // [4096,1024]

    cast_bf16<<<(B_ * T_ * D_) / (8 * 256), 256, 0, stream>>>(X, Xb);
    transpose_cast<<<dim3((3 * D_) / 64, D_ / 64), 256, 0, stream>>>(W_KQV, Wt, D_, 3 * D_);
    transpose_cast<<<dim3(D_ / 64, D_ / 64), 256, 0, stream>>>(W_out, Wot, D_, D_);

    gemm_bt<unsigned short><<<dim3((3 * D_) / 128, (B_ * T_) / 128), 256, 0, stream>>>(
        Xb, Wt, resb, B_ * T_, 3 * D_, D_);

    transpose_v<<<dim3(T_ / 64, B_ * H_), 256, 0, stream>>>(resb, Vt);

    attn_fused<<<dim3(16, B_ * H_), 256, 0, stream>>>(resb, Vt, attn, ctxb);

    gemm_bt<float><<<dim3(D_ / 128, (B_ * T_) / 128), 256, 0, stream>>>(
        ctxb, Wot, out, B_ * T_, D_, D_);
}